// Round 1
// baseline (1036.492 us; speedup 1.0000x reference)
//
#include <hip/hip_runtime.h>

#define DIM 128
#define K_CL 512
#define BM 128          // points per block tile
#define BK 128          // centers per chunk
#define TM 8            // points per thread
#define TN 8            // centers per thread
#define LDF 132         // padded LDS row stride (floats): breaks bank alignment, keeps 16B align
#define TAU 0.02f       // fp32 margin below which we recompute in fp64
#define RESCUE_CAP 16384
#define P_PART 32       // point partitions for segment-sum

// ---------------- kernel A: c2[k] = ||centers[k]||^2 ----------------
__global__ void c2_kernel(const float* __restrict__ C, float* __restrict__ c2) {
    int k = blockIdx.x * 256 + threadIdx.x;
    if (k < K_CL) {
        float s = 0.f;
        const float* row = C + (size_t)k * DIM;
        for (int d = 0; d < DIM; ++d) s = fmaf(row[d], row[d], s);
        c2[k] = s;
    }
}

// ---------------- kernel B: fused distance GEMM + argmin ----------------
// block tile: 128 points x 512 centers (4 chunks of 128), thread tile 8x8.
// d2 = c2[k] - 2*dot(F[p],C[k])  (f2 term dropped: argmin-invariant; rounding
// differences vs reference are absorbed by the fp64 rescue pass)
__global__ __launch_bounds__(256, 1)
void assign_kernel(const float* __restrict__ F, const float* __restrict__ C,
                   const float* __restrict__ c2g, float* __restrict__ assign_out,
                   int* __restrict__ rescueCnt, int* __restrict__ rescueLst, int N) {
    __shared__ float Fs[BM * LDF];   // 67584 B
    __shared__ float Cs[BK * LDF];   // 67584 B
    __shared__ float c2s[BK];

    int tid = threadIdx.x;
    int tx = tid & 15;
    int ty = tid >> 4;
    int p0 = blockIdx.x * BM;

    // stage F tile: contiguous 128x128 floats -> padded LDS, float4
    for (int s = 0; s < 16; ++s) {
        int e4 = tid + 256 * s;          // 0..4095 float4s
        int row = e4 >> 5;               // /32 float4s per row
        int c4  = e4 & 31;
        int gp = p0 + row; if (gp >= N) gp = N - 1;   // clamp (writes are guarded)
        float4 v = ((const float4*)(F + (size_t)gp * DIM))[c4];
        *((float4*)(Fs + row * LDF + c4 * 4)) = v;
    }

    float best1[TM], best2[TM];
    int bidx[TM];
#pragma unroll
    for (int i = 0; i < TM; ++i) { best1[i] = 3.4e38f; best2[i] = 3.4e38f; bidx[i] = 0; }

    for (int ch = 0; ch < K_CL / BK; ++ch) {
        __syncthreads();   // previous chunk fully consumed before overwrite
        int k0 = ch * BK;
        for (int s = 0; s < 16; ++s) {
            int e4 = tid + 256 * s;
            int row = e4 >> 5;
            int c4  = e4 & 31;
            float4 v = ((const float4*)(C + (size_t)(k0 + row) * DIM))[c4];
            *((float4*)(Cs + row * LDF + c4 * 4)) = v;
        }
        if (tid < BK) c2s[tid] = c2g[k0 + tid];
        __syncthreads();

        float acc[TM][TN];
#pragma unroll
        for (int i = 0; i < TM; ++i)
#pragma unroll
            for (int j = 0; j < TN; ++j) acc[i][j] = 0.f;

#pragma unroll 2
        for (int d4 = 0; d4 < DIM / 4; ++d4) {
            float4 a[TM], b[TN];
#pragma unroll
            for (int i = 0; i < TM; ++i)
                a[i] = *((const float4*)(Fs + (ty + 16 * i) * LDF + d4 * 4));
#pragma unroll
            for (int j = 0; j < TN; ++j)
                b[j] = *((const float4*)(Cs + (tx + 16 * j) * LDF + d4 * 4));
#pragma unroll
            for (int i = 0; i < TM; ++i)
#pragma unroll
                for (int j = 0; j < TN; ++j) {
                    acc[i][j] = fmaf(a[i].x, b[j].x, acc[i][j]);
                    acc[i][j] = fmaf(a[i].y, b[j].y, acc[i][j]);
                    acc[i][j] = fmaf(a[i].z, b[j].z, acc[i][j]);
                    acc[i][j] = fmaf(a[i].w, b[j].w, acc[i][j]);
                }
        }

        // epilogue: running best / second-best (k ascending within thread)
#pragma unroll
        for (int i = 0; i < TM; ++i) {
#pragma unroll
            for (int j = 0; j < TN; ++j) {
                int k = k0 + tx + 16 * j;
                float d = c2s[tx + 16 * j] - 2.0f * acc[i][j];
                if (d < best1[i]) { best2[i] = best1[i]; best1[i] = d; bidx[i] = k; }
                else if (d < best2[i]) best2[i] = d;
            }
        }
    }

    // reduce across the 16 tx lanes (lane bits 0..3) with first-index tie-break
#pragma unroll
    for (int i = 0; i < TM; ++i) {
        float b1 = best1[i], b2 = best2[i];
        int k1 = bidx[i];
        for (int m = 1; m <= 8; m <<= 1) {
            float ob1 = __shfl_xor(b1, m);
            float ob2 = __shfl_xor(b2, m);
            int   ok1 = __shfl_xor(k1, m);
            float nb2 = fminf(fmaxf(b1, ob1), fminf(b2, ob2));
            if (ob1 < b1 || (ob1 == b1 && ok1 < k1)) { b1 = ob1; k1 = ok1; }
            b2 = nb2;
        }
        if (tx == 0) {
            int gp = p0 + ty + 16 * i;
            if (gp < N) {
                assign_out[gp] = (float)k1;
                if (b2 - b1 < TAU) {
                    int idx = atomicAdd(rescueCnt, 1);
                    if (idx < RESCUE_CAP) rescueLst[idx] = gp;
                }
            }
        }
    }
}

// ---------------- kernel C: fp64 re-argmin for near-tie points ----------------
__global__ void rescue_kernel(const float* __restrict__ F, const float* __restrict__ C,
                              const int* __restrict__ rescueCnt,
                              const int* __restrict__ rescueLst,
                              float* __restrict__ assign_out) {
    __shared__ double Frow[DIM];
    __shared__ double bd[256];
    __shared__ int    bk[256];
    int cnt = *rescueCnt;
    if (cnt > RESCUE_CAP) cnt = RESCUE_CAP;
    for (int r = blockIdx.x; r < cnt; r += gridDim.x) {
        int p = rescueLst[r];
        if (threadIdx.x < DIM) Frow[threadIdx.x] = (double)F[(size_t)p * DIM + threadIdx.x];
        __syncthreads();
        double b1 = 1e300; int k1 = 0x7fffffff;
        for (int k = threadIdx.x; k < K_CL; k += 256) {
            const float* c = C + (size_t)k * DIM;
            double acc = 0.0, cc = 0.0;
            for (int d = 0; d < DIM; ++d) {
                double cv = (double)c[d];
                acc += Frow[d] * cv;
                cc  += cv * cv;
            }
            double dd = cc - 2.0 * acc;
            if (dd < b1 || (dd == b1 && k < k1)) { b1 = dd; k1 = k; }
        }
        bd[threadIdx.x] = b1; bk[threadIdx.x] = k1;
        __syncthreads();
        for (int s = 128; s > 0; s >>= 1) {
            if (threadIdx.x < s) {
                double ob = bd[threadIdx.x + s]; int ok = bk[threadIdx.x + s];
                if (ob < bd[threadIdx.x] || (ob == bd[threadIdx.x] && ok < bk[threadIdx.x])) {
                    bd[threadIdx.x] = ob; bk[threadIdx.x] = ok;
                }
            }
            __syncthreads();
        }
        if (threadIdx.x == 0) assign_out[p] = (float)bk[0];
        __syncthreads();
    }
}

// ---------------- kernel D: segment sum + counts via LDS histogram ----------------
// grid = 4 dim-ranges x P_PART point partitions; LDS acc[512][32]
__global__ __launch_bounds__(256, 2)
void segsum_kernel(const float* __restrict__ F, const float* __restrict__ assign_f,
                   float* __restrict__ sums, float* __restrict__ counts, int N) {
    __shared__ float acc[K_CL * 32];    // 64 KB
    __shared__ float cnt[K_CL];
    int drange = blockIdx.x & 3;
    int part   = blockIdx.x >> 2;
    for (int i = threadIdx.x; i < K_CL * 32; i += 256) acc[i] = 0.f;
    if (drange == 0)
        for (int i = threadIdx.x; i < K_CL; i += 256) cnt[i] = 0.f;
    __syncthreads();

    int per = (N + P_PART - 1) / P_PART;
    int s0 = part * per;
    int s1 = s0 + per; if (s1 > N) s1 = N;
    int d   = threadIdx.x & 31;
    int sub = threadIdx.x >> 5;          // 0..7 points per iteration
    int d0  = drange * 32;
    for (int p = s0 + sub; p < s1; p += 8) {
        int a = (int)assign_f[p];
        float v = F[(size_t)p * DIM + d0 + d];
        atomicAdd(&acc[a * 32 + d], v);
        if (drange == 0 && d == 0) atomicAdd(&cnt[a], 1.f);
    }
    __syncthreads();
    for (int i = threadIdx.x; i < K_CL * 32; i += 256) {
        int k = i >> 5, dd = i & 31;
        unsafeAtomicAdd(&sums[k * DIM + d0 + dd], acc[i]);
    }
    if (drange == 0)
        for (int i = threadIdx.x; i < K_CL; i += 256) unsafeAtomicAdd(&counts[i], cnt[i]);
}

// ---------------- kernel E: new_centers = sums / max(counts,1) ----------------
__global__ void finalize_kernel(const float* __restrict__ sums,
                                const float* __restrict__ counts,
                                float* __restrict__ out) {
    int i = blockIdx.x * 256 + threadIdx.x;   // 0..65535
    int k = i >> 7;
    out[i] = sums[i] / fmaxf(counts[k], 1.0f);
}

extern "C" void kernel_launch(void* const* d_in, const int* in_sizes, int n_in,
                              void* d_out, int out_size, void* d_ws, size_t ws_size,
                              hipStream_t stream) {
    const float* F = (const float*)d_in[0];
    const float* C = (const float*)d_in[1];
    int N = in_sizes[0] / DIM;               // 200000

    float* out = (float*)d_out;
    float* centers_out = out;                // [512*128]
    float* assign_out  = out + K_CL * DIM;   // [N], written as float

    // workspace layout (total ~332 KB)
    float* sums      = (float*)d_ws;                 // 512*128
    float* counts    = sums + K_CL * DIM;            // 512
    int*   rescueCnt = (int*)(counts + K_CL);        // 4 ints (use [0])
    int*   rescueLst = rescueCnt + 4;                // RESCUE_CAP
    float* c2        = (float*)(rescueLst + RESCUE_CAP);  // 512

    // zero sums + counts + rescueCnt (ws is poisoned 0xAA before every launch)
    hipMemsetAsync(d_ws, 0, (size_t)(K_CL * DIM + K_CL) * sizeof(float) + 16, stream);

    c2_kernel<<<2, 256, 0, stream>>>(C, c2);

    int nb = (N + BM - 1) / BM;              // 1563
    assign_kernel<<<nb, 256, 0, stream>>>(F, C, c2, assign_out, rescueCnt, rescueLst, N);

    rescue_kernel<<<128, 256, 0, stream>>>(F, C, rescueCnt, rescueLst, assign_out);

    segsum_kernel<<<4 * P_PART, 256, 0, stream>>>(F, assign_out, sums, counts, N);

    finalize_kernel<<<K_CL * DIM / 256, 256, 0, stream>>>(sums, counts, centers_out);
}

// Round 2
// 615.849 us; speedup vs baseline: 1.6830x; 1.6830x over previous
//
#include <hip/hip_runtime.h>

#define DIM 128
#define K_CL 512
#define BM 128          // points per block tile
#define CC 128          // centers per chunk (4 chunks)
#define TAU 0.02f       // margin below which we recompute in fp64
#define RESCUE_CAP 16384
#define P_PART 32       // point partitions for segment-sum

typedef unsigned int uint;
typedef unsigned short ushort;
using short8 = __attribute__((ext_vector_type(8))) short;
using f32x4  = __attribute__((ext_vector_type(4))) float;
using us8    = __attribute__((ext_vector_type(8))) unsigned short;

__device__ __forceinline__ ushort f2bf(float x) {
    uint u = __float_as_uint(x);
    u += 0x7fff + ((u >> 16) & 1);          // RNE
    return (ushort)(u >> 16);
}
__device__ __forceinline__ float bf2f(ushort h) {
    return __uint_as_float(((uint)h) << 16);
}

__device__ __forceinline__ void gload_lds16(const void* gsrc, void* ldst) {
    __builtin_amdgcn_global_load_lds(
        (const __attribute__((address_space(1))) unsigned int*)gsrc,
        (__attribute__((address_space(3))) unsigned int*)ldst,
        16, 0, 0);
}

// ---------------- kernel A: c2 (fp32) and c2d (fp64) ----------------
__global__ void c2_kernel(const float* __restrict__ C, float* __restrict__ c2,
                          double* __restrict__ c2d) {
    int k = blockIdx.x * 256 + threadIdx.x;
    if (k < K_CL) {
        const float* row = C + (size_t)k * DIM;
        float s = 0.f;
        double sd = 0.0;
        for (int d = 0; d < DIM; ++d) {
            s = fmaf(row[d], row[d], s);
            double v = (double)row[d];
            sd += v * v;
        }
        c2[k] = s;
        c2d[k] = sd;
    }
}

// ---------------- kernel A2: split C into bf16 hi|lo ----------------
// Cp[k][0:128] = hi, Cp[k][128:256] = lo
__global__ void convC_kernel(const float* __restrict__ C, ushort* __restrict__ Cp) {
    int e = blockIdx.x * 256 + threadIdx.x;   // 0..65535
    if (e < K_CL * DIM) {
        int p = e >> 7, d = e & 127;
        float x = C[e];
        ushort h = f2bf(x);
        float lo = x - bf2f(h);
        Cp[(size_t)p * 256 + d] = h;
        Cp[(size_t)p * 256 + 128 + d] = f2bf(lo);
    }
}

// ---------------- kernel B: MFMA distance GEMM + argmin ----------------
// virtual K = 384: hiF*hiC (k 0-127) + loF*hiC + hiF*loC, in 6 chunks of 64.
// Fs: 128 rows x 32 granules(16B), granule g of row r stored at
//     pos = (g&24) | ((g&7)^(r&7))  -> conflict-free ds_read_b128.
// Cs: 128 rows x 8 granules, same swizzle, staged via global_load_lds.
__global__ __launch_bounds__(256, 2)
void assign_mfma(const float* __restrict__ F, const ushort* __restrict__ Cp,
                 const float* __restrict__ c2g, float* __restrict__ assign_out,
                 int* __restrict__ rescueCnt, int* __restrict__ rescueLst, int N) {
    __shared__ __align__(16) ushort Fs[BM * 256];   // 65536 B
    __shared__ __align__(16) ushort Cs[CC * 64];    // 16384 B

    const int tid  = threadIdx.x;
    const int lane = tid & 63;
    const int wave = tid >> 6;
    const int quad = lane >> 4;
    const int l15  = lane & 15;
    const int wy   = wave >> 1;     // point half (0,1)
    const int wx   = wave & 1;      // center half (0,1)
    const int p0   = blockIdx.x * BM;

    // ---- stage Fs: read fp32 F, split to bf16 hi/lo, swizzled store ----
    for (int G = tid; G < BM * 32; G += 256) {
        int r = G >> 5, pos = G & 31;
        int g = (pos & 24) | ((pos ^ r) & 7);
        int gp = p0 + r; if (gp >= N) gp = N - 1;
        const float* src = F + (size_t)gp * DIM + (g & 15) * 8;
        float4 x0 = ((const float4*)src)[0];
        float4 x1 = ((const float4*)src)[1];
        float xs[8] = {x0.x, x0.y, x0.z, x0.w, x1.x, x1.y, x1.z, x1.w};
        us8 o;
        if (g < 16) {
#pragma unroll
            for (int t = 0; t < 8; ++t) o[t] = f2bf(xs[t]);
        } else {
#pragma unroll
            for (int t = 0; t < 8; ++t) {
                ushort h = f2bf(xs[t]);
                o[t] = f2bf(xs[t] - bf2f(h));
            }
        }
        *((us8*)&Fs[(size_t)G * 8]) = o;
    }

    const int akmap[6] = {0, 1, 2, 3, 0, 1};   // A chunk (of Fs 4x64)
    const int ckmap[6] = {0, 1, 0, 1, 2, 3};   // C chunk (of Cp row 4x64)

    float best1[16], best2[16];
    int bidx[16];
#pragma unroll
    for (int i = 0; i < 16; ++i) { best1[i] = 3.4e38f; best2[i] = 3.4e38f; bidx[i] = 0; }

    for (int cc = 0; cc < K_CL / CC; ++cc) {
        f32x4 acc[4][4];
#pragma unroll
        for (int i = 0; i < 4; ++i)
#pragma unroll
            for (int j = 0; j < 4; ++j) acc[i][j] = f32x4{0.f, 0.f, 0.f, 0.f};

        for (int v = 0; v < 6; ++v) {
            __syncthreads();   // Cs consumed by previous iter
            // stage Cs chunk: 1024 granules, 4 rounds x (4 waves x 64 lanes)
            {
                int ckb = ckmap[v] * 64;
#pragma unroll
                for (int t = 0; t < 4; ++t) {
                    int Gbase = t * 256 + wave * 64;       // wave-uniform
                    int G = Gbase + lane;
                    int r = G >> 3, pos = G & 7;
                    int g = pos ^ (r & 7);
                    const ushort* gsrc = Cp + (size_t)(cc * CC + r) * 256 + ckb + g * 8;
                    gload_lds16(gsrc, &Cs[(size_t)Gbase * 8]);
                }
            }
            __syncthreads();   // staging complete (vmcnt drain)

            int ak = akmap[v];
#pragma unroll
            for (int s = 0; s < 2; ++s) {
                short8 a[4], b[4];
#pragma unroll
                for (int i = 0; i < 4; ++i) {
                    int pr = wy * 64 + i * 16 + l15;
                    int posA = ak * 8 + ((s * 4 + quad) ^ (pr & 7));
                    a[i] = *((const short8*)&Fs[(size_t)(pr * 32 + posA) * 8]);
                }
#pragma unroll
                for (int j = 0; j < 4; ++j) {
                    int cn = wx * 64 + j * 16 + l15;
                    int posB = (s * 4 + quad) ^ (cn & 7);
                    b[j] = *((const short8*)&Cs[(size_t)(cn * 8 + posB) * 8]);
                }
#pragma unroll
                for (int i = 0; i < 4; ++i)
#pragma unroll
                    for (int j = 0; j < 4; ++j)
                        acc[i][j] = __builtin_amdgcn_mfma_f32_16x16x32_bf16(
                            a[i], b[j], acc[i][j], 0, 0, 0);
            }
        }

        // ---- epilogue for this center chunk: fold into best1/best2 ----
        float c2v[4];
#pragma unroll
        for (int j = 0; j < 4; ++j)
            c2v[j] = c2g[cc * CC + wx * 64 + j * 16 + l15];
#pragma unroll
        for (int i = 0; i < 4; ++i)
#pragma unroll
            for (int reg = 0; reg < 4; ++reg) {
                int lr = i * 4 + reg;
#pragma unroll
                for (int j = 0; j < 4; ++j) {
                    float d = c2v[j] - 2.0f * acc[i][j][reg];
                    int k = cc * CC + wx * 64 + j * 16 + l15;
                    if (d < best1[lr]) { best2[lr] = best1[lr]; best1[lr] = d; bidx[lr] = k; }
                    else if (d < best2[lr]) best2[lr] = d;
                }
            }
    }

    // ---- reduce across the 16 l15 lanes (same quad holds same rows) ----
    __syncthreads();            // done with Cs; reuse as merge scratch
    float* sb1 = (float*)Cs;                 // [2][128]
    float* sb2 = sb1 + 256;                  // [2][128]
    int*   sk  = (int*)(sb2 + 256);          // [2][128]

#pragma unroll
    for (int lr = 0; lr < 16; ++lr) {
        float b1 = best1[lr], b2 = best2[lr];
        int k1 = bidx[lr];
#pragma unroll
        for (int m = 1; m <= 8; m <<= 1) {
            float ob1 = __shfl_xor(b1, m);
            float ob2 = __shfl_xor(b2, m);
            int   ok1 = __shfl_xor(k1, m);
            float nb2 = fminf(fmaxf(b1, ob1), fminf(b2, ob2));
            if (ob1 < b1 || (ob1 == b1 && ok1 < k1)) { b1 = ob1; k1 = ok1; }
            b2 = nb2;
        }
        best1[lr] = b1; best2[lr] = b2; bidx[lr] = k1;
    }
    if (l15 == 0) {
#pragma unroll
        for (int lr = 0; lr < 16; ++lr) {
            int pl = wy * 64 + (lr >> 2) * 16 + quad * 4 + (lr & 3);
            sb1[wx * 128 + pl] = best1[lr];
            sb2[wx * 128 + pl] = best2[lr];
            sk [wx * 128 + pl] = bidx[lr];
        }
    }
    __syncthreads();

    // ---- merge the two center-half waves, write assign + rescue ----
    if (tid < BM) {
        int p = p0 + tid;
        if (p < N) {
            float a1 = sb1[tid],       a2 = sb2[tid];       int akk = sk[tid];
            float c1 = sb1[128 + tid], cs2 = sb2[128 + tid]; int ckk = sk[128 + tid];
            float m2 = fminf(fmaxf(a1, c1), fminf(a2, cs2));
            float m1; int mk;
            if (c1 < a1 || (c1 == a1 && ckk < akk)) { m1 = c1; mk = ckk; }
            else                                    { m1 = a1; mk = akk; }
            assign_out[p] = (float)mk;
            if (m2 - m1 < TAU) {
                int idx = atomicAdd(rescueCnt, 1);
                if (idx < RESCUE_CAP) rescueLst[idx] = p;
            }
        }
    }
}

// ---------------- kernel C: fp64 re-argmin for near-tie points ----------------
__global__ void rescue_kernel(const float* __restrict__ F, const float* __restrict__ C,
                              const double* __restrict__ c2d,
                              const int* __restrict__ rescueCnt,
                              const int* __restrict__ rescueLst,
                              float* __restrict__ assign_out) {
    __shared__ double Frow[DIM];
    __shared__ double bd[256];
    __shared__ int    bk[256];
    int cnt = *rescueCnt;
    if (cnt > RESCUE_CAP) cnt = RESCUE_CAP;
    for (int r = blockIdx.x; r < cnt; r += gridDim.x) {
        int p = rescueLst[r];
        if (threadIdx.x < DIM) Frow[threadIdx.x] = (double)F[(size_t)p * DIM + threadIdx.x];
        __syncthreads();
        double b1 = 1e300; int k1 = 0x7fffffff;
        for (int k = threadIdx.x; k < K_CL; k += 256) {
            const float* c = C + (size_t)k * DIM;
            double acc = 0.0;
            for (int d = 0; d < DIM; ++d) acc += Frow[d] * (double)c[d];
            double dd = c2d[k] - 2.0 * acc;
            if (dd < b1 || (dd == b1 && k < k1)) { b1 = dd; k1 = k; }
        }
        bd[threadIdx.x] = b1; bk[threadIdx.x] = k1;
        __syncthreads();
        for (int s = 128; s > 0; s >>= 1) {
            if (threadIdx.x < s) {
                double ob = bd[threadIdx.x + s]; int ok = bk[threadIdx.x + s];
                if (ob < bd[threadIdx.x] || (ob == bd[threadIdx.x] && ok < bk[threadIdx.x])) {
                    bd[threadIdx.x] = ob; bk[threadIdx.x] = ok;
                }
            }
            __syncthreads();
        }
        if (threadIdx.x == 0) assign_out[p] = (float)bk[0];
        __syncthreads();
    }
}

// ---------------- kernel D: segment sum + counts via LDS histogram ----------------
__global__ __launch_bounds__(256, 2)
void segsum_kernel(const float* __restrict__ F, const float* __restrict__ assign_f,
                   float* __restrict__ sums, float* __restrict__ counts, int N) {
    __shared__ float acc[K_CL * 32];    // 64 KB
    __shared__ float cnt[K_CL];
    int drange = blockIdx.x & 3;
    int part   = blockIdx.x >> 2;
    for (int i = threadIdx.x; i < K_CL * 32; i += 256) acc[i] = 0.f;
    if (drange == 0)
        for (int i = threadIdx.x; i < K_CL; i += 256) cnt[i] = 0.f;
    __syncthreads();

    int per = (N + P_PART - 1) / P_PART;
    int s0 = part * per;
    int s1 = s0 + per; if (s1 > N) s1 = N;
    int d   = threadIdx.x & 31;
    int sub = threadIdx.x >> 5;
    int d0  = drange * 32;
    for (int p = s0 + sub; p < s1; p += 8) {
        int a = (int)assign_f[p];
        float v = F[(size_t)p * DIM + d0 + d];
        atomicAdd(&acc[a * 32 + d], v);
        if (drange == 0 && d == 0) atomicAdd(&cnt[a], 1.f);
    }
    __syncthreads();
    for (int i = threadIdx.x; i < K_CL * 32; i += 256) {
        int k = i >> 5, dd = i & 31;
        unsafeAtomicAdd(&sums[k * DIM + d0 + dd], acc[i]);
    }
    if (drange == 0)
        for (int i = threadIdx.x; i < K_CL; i += 256) unsafeAtomicAdd(&counts[i], cnt[i]);
}

// ---------------- kernel E: new_centers = sums / max(counts,1) ----------------
__global__ void finalize_kernel(const float* __restrict__ sums,
                                const float* __restrict__ counts,
                                float* __restrict__ out) {
    int i = blockIdx.x * 256 + threadIdx.x;   // 0..65535
    int k = i >> 7;
    out[i] = sums[i] / fmaxf(counts[k], 1.0f);
}

extern "C" void kernel_launch(void* const* d_in, const int* in_sizes, int n_in,
                              void* d_out, int out_size, void* d_ws, size_t ws_size,
                              hipStream_t stream) {
    const float* F = (const float*)d_in[0];
    const float* C = (const float*)d_in[1];
    int N = in_sizes[0] / DIM;               // 200000

    float* out = (float*)d_out;
    float* centers_out = out;                // [512*128]
    float* assign_out  = out + K_CL * DIM;   // [N], as float

    // workspace layout (~600 KB)
    float*  sums      = (float*)d_ws;                     // 65536 f
    float*  counts    = sums + K_CL * DIM;                // 512 f
    int*    rescueCnt = (int*)(counts + K_CL);            // 4 i
    int*    rescueLst = rescueCnt + 4;                    // 16384 i
    float*  c2        = (float*)(rescueLst + RESCUE_CAP); // 512 f
    double* c2d       = (double*)(c2 + K_CL);             // 512 d (8B aligned)
    ushort* Cp        = (ushort*)(c2d + K_CL);            // 512*256 us (16B aligned)

    hipMemsetAsync(d_ws, 0, (size_t)(K_CL * DIM + K_CL) * sizeof(float) + 16, stream);

    c2_kernel<<<2, 256, 0, stream>>>(C, c2, c2d);
    convC_kernel<<<K_CL * DIM / 256, 256, 0, stream>>>(C, Cp);

    int nb = (N + BM - 1) / BM;              // 1563
    assign_mfma<<<nb, 256, 0, stream>>>(F, Cp, c2, assign_out, rescueCnt, rescueLst, N);

    rescue_kernel<<<256, 256, 0, stream>>>(F, C, c2d, rescueCnt, rescueLst, assign_out);

    segsum_kernel<<<4 * P_PART, 256, 0, stream>>>(F, assign_out, sums, counts, N);

    finalize_kernel<<<K_CL * DIM / 256, 256, 0, stream>>>(sums, counts, centers_out);
}

// Round 3
// 550.801 us; speedup vs baseline: 1.8818x; 1.1181x over previous
//
#include <hip/hip_runtime.h>

#define DIM 128
#define K_CL 512
#define BM 128          // points per block tile
#define CC 128          // centers per chunk (4 chunks)
#define TAU 0.02f       // margin below which we recompute in fp64
#define RESCUE_CAP 16384
#define SS_PARTS 128    // point partitions for segment-sum
#define QCAP 2048

typedef unsigned int uint;
typedef unsigned short ushort;
using short8 = __attribute__((ext_vector_type(8))) short;
using f32x4  = __attribute__((ext_vector_type(4))) float;
using us8    = __attribute__((ext_vector_type(8))) unsigned short;

__device__ __forceinline__ ushort f2bf(float x) {
    uint u = __float_as_uint(x);
    u += 0x7fff + ((u >> 16) & 1);          // RNE
    return (ushort)(u >> 16);
}
__device__ __forceinline__ float bf2f(ushort h) {
    return __uint_as_float(((uint)h) << 16);
}

__device__ __forceinline__ void gload_lds16(const void* gsrc, void* ldst) {
    __builtin_amdgcn_global_load_lds(
        (const __attribute__((address_space(1))) unsigned int*)gsrc,
        (__attribute__((address_space(3))) unsigned int*)ldst,
        16, 0, 0);
}

// ---------------- kernel A: c2 (fp32) and c2d (fp64) ----------------
__global__ void c2_kernel(const float* __restrict__ C, float* __restrict__ c2,
                          double* __restrict__ c2d) {
    int k = blockIdx.x * 256 + threadIdx.x;
    if (k < K_CL) {
        const float* row = C + (size_t)k * DIM;
        float s = 0.f;
        double sd = 0.0;
        for (int d = 0; d < DIM; ++d) {
            s = fmaf(row[d], row[d], s);
            double v = (double)row[d];
            sd += v * v;
        }
        c2[k] = s;
        c2d[k] = sd;
    }
}

// ---------------- kernel A2: split C into bf16 hi|lo ----------------
__global__ void convC_kernel(const float* __restrict__ C, ushort* __restrict__ Cp) {
    int e = blockIdx.x * 256 + threadIdx.x;   // 0..65535
    if (e < K_CL * DIM) {
        int p = e >> 7, d = e & 127;
        float x = C[e];
        ushort h = f2bf(x);
        float lo = x - bf2f(h);
        Cp[(size_t)p * 256 + d] = h;
        Cp[(size_t)p * 256 + 128 + d] = f2bf(lo);
    }
}

// ---------------- kernel B: MFMA distance GEMM + argmin ----------------
__global__ __launch_bounds__(256, 2)
void assign_mfma(const float* __restrict__ F, const ushort* __restrict__ Cp,
                 const float* __restrict__ c2g, float* __restrict__ assign_out,
                 int* __restrict__ rescueCnt, int* __restrict__ rescueLst, int N) {
    __shared__ __align__(16) ushort Fs[BM * 256];   // 65536 B
    __shared__ __align__(16) ushort Cs[CC * 64];    // 16384 B

    const int tid  = threadIdx.x;
    const int lane = tid & 63;
    const int wave = tid >> 6;
    const int quad = lane >> 4;
    const int l15  = lane & 15;
    const int wy   = wave >> 1;     // point half (0,1)
    const int wx   = wave & 1;      // center half (0,1)
    const int p0   = blockIdx.x * BM;

    // ---- stage Fs: read fp32 F, split to bf16 hi/lo, swizzled store ----
    for (int G = tid; G < BM * 32; G += 256) {
        int r = G >> 5, pos = G & 31;
        int g = (pos & 24) | ((pos ^ r) & 7);
        int gp = p0 + r; if (gp >= N) gp = N - 1;
        const float* src = F + (size_t)gp * DIM + (g & 15) * 8;
        float4 x0 = ((const float4*)src)[0];
        float4 x1 = ((const float4*)src)[1];
        float xs[8] = {x0.x, x0.y, x0.z, x0.w, x1.x, x1.y, x1.z, x1.w};
        us8 o;
        if (g < 16) {
#pragma unroll
            for (int t = 0; t < 8; ++t) o[t] = f2bf(xs[t]);
        } else {
#pragma unroll
            for (int t = 0; t < 8; ++t) {
                ushort h = f2bf(xs[t]);
                o[t] = f2bf(xs[t] - bf2f(h));
            }
        }
        *((us8*)&Fs[(size_t)G * 8]) = o;
    }

    const int akmap[6] = {0, 1, 2, 3, 0, 1};   // A chunk (of Fs 4x64)
    const int ckmap[6] = {0, 1, 0, 1, 2, 3};   // C chunk (of Cp row 4x64)

    float best1[16], best2[16];
    int bidx[16];
#pragma unroll
    for (int i = 0; i < 16; ++i) { best1[i] = 3.4e38f; best2[i] = 3.4e38f; bidx[i] = 0; }

    for (int cc = 0; cc < K_CL / CC; ++cc) {
        f32x4 acc[4][4];
#pragma unroll
        for (int i = 0; i < 4; ++i)
#pragma unroll
            for (int j = 0; j < 4; ++j) acc[i][j] = f32x4{0.f, 0.f, 0.f, 0.f};

        for (int v = 0; v < 6; ++v) {
            __syncthreads();   // Cs consumed by previous iter
            {
                int ckb = ckmap[v] * 64;
#pragma unroll
                for (int t = 0; t < 4; ++t) {
                    int Gbase = t * 256 + wave * 64;       // wave-uniform
                    int G = Gbase + lane;
                    int r = G >> 3, pos = G & 7;
                    int g = pos ^ (r & 7);
                    const ushort* gsrc = Cp + (size_t)(cc * CC + r) * 256 + ckb + g * 8;
                    gload_lds16(gsrc, &Cs[(size_t)Gbase * 8]);
                }
            }
            __syncthreads();   // staging complete

            int ak = akmap[v];
#pragma unroll
            for (int s = 0; s < 2; ++s) {
                short8 a[4], b[4];
#pragma unroll
                for (int i = 0; i < 4; ++i) {
                    int pr = wy * 64 + i * 16 + l15;
                    int posA = ak * 8 + ((s * 4 + quad) ^ (pr & 7));
                    a[i] = *((const short8*)&Fs[(size_t)(pr * 32 + posA) * 8]);
                }
#pragma unroll
                for (int j = 0; j < 4; ++j) {
                    int cn = wx * 64 + j * 16 + l15;
                    int posB = (s * 4 + quad) ^ (cn & 7);
                    b[j] = *((const short8*)&Cs[(size_t)(cn * 8 + posB) * 8]);
                }
#pragma unroll
                for (int i = 0; i < 4; ++i)
#pragma unroll
                    for (int j = 0; j < 4; ++j)
                        acc[i][j] = __builtin_amdgcn_mfma_f32_16x16x32_bf16(
                            a[i], b[j], acc[i][j], 0, 0, 0);
            }
        }

        // ---- epilogue for this center chunk ----
        float c2v[4];
#pragma unroll
        for (int j = 0; j < 4; ++j)
            c2v[j] = c2g[cc * CC + wx * 64 + j * 16 + l15];
#pragma unroll
        for (int i = 0; i < 4; ++i)
#pragma unroll
            for (int reg = 0; reg < 4; ++reg) {
                int lr = i * 4 + reg;
#pragma unroll
                for (int j = 0; j < 4; ++j) {
                    float d = c2v[j] - 2.0f * acc[i][j][reg];
                    int k = cc * CC + wx * 64 + j * 16 + l15;
                    if (d < best1[lr]) { best2[lr] = best1[lr]; best1[lr] = d; bidx[lr] = k; }
                    else if (d < best2[lr]) best2[lr] = d;
                }
            }
    }

    // ---- reduce across the 16 l15 lanes ----
    __syncthreads();
    float* sb1 = (float*)Cs;                 // [2][128]
    float* sb2 = sb1 + 256;
    int*   sk  = (int*)(sb2 + 256);

#pragma unroll
    for (int lr = 0; lr < 16; ++lr) {
        float b1 = best1[lr], b2 = best2[lr];
        int k1 = bidx[lr];
#pragma unroll
        for (int m = 1; m <= 8; m <<= 1) {
            float ob1 = __shfl_xor(b1, m);
            float ob2 = __shfl_xor(b2, m);
            int   ok1 = __shfl_xor(k1, m);
            float nb2 = fminf(fmaxf(b1, ob1), fminf(b2, ob2));
            if (ob1 < b1 || (ob1 == b1 && ok1 < k1)) { b1 = ob1; k1 = ok1; }
            b2 = nb2;
        }
        best1[lr] = b1; best2[lr] = b2; bidx[lr] = k1;
    }
    if (l15 == 0) {
#pragma unroll
        for (int lr = 0; lr < 16; ++lr) {
            int pl = wy * 64 + (lr >> 2) * 16 + quad * 4 + (lr & 3);
            sb1[wx * 128 + pl] = best1[lr];
            sb2[wx * 128 + pl] = best2[lr];
            sk [wx * 128 + pl] = bidx[lr];
        }
    }
    __syncthreads();

    if (tid < BM) {
        int p = p0 + tid;
        if (p < N) {
            float a1 = sb1[tid],       a2 = sb2[tid];        int akk = sk[tid];
            float c1 = sb1[128 + tid], cs2 = sb2[128 + tid]; int ckk = sk[128 + tid];
            float m2 = fminf(fmaxf(a1, c1), fminf(a2, cs2));
            float m1; int mk;
            if (c1 < a1 || (c1 == a1 && ckk < akk)) { m1 = c1; mk = ckk; }
            else                                    { m1 = a1; mk = akk; }
            assign_out[p] = (float)mk;
            if (m2 - m1 < TAU) {
                int idx = atomicAdd(rescueCnt, 1);
                if (idx < RESCUE_CAP) rescueLst[idx] = p;
            }
        }
    }
}

// ---------------- kernel C: fp64 re-argmin for near-tie points ----------------
__global__ void rescue_kernel(const float* __restrict__ F, const float* __restrict__ C,
                              const double* __restrict__ c2d,
                              const int* __restrict__ rescueCnt,
                              const int* __restrict__ rescueLst,
                              float* __restrict__ assign_out) {
    __shared__ double Frow[DIM];
    __shared__ double bd[256];
    __shared__ int    bk[256];
    int cnt = *rescueCnt;
    if (cnt > RESCUE_CAP) cnt = RESCUE_CAP;
    for (int r = blockIdx.x; r < cnt; r += gridDim.x) {
        int p = rescueLst[r];
        if (threadIdx.x < DIM) Frow[threadIdx.x] = (double)F[(size_t)p * DIM + threadIdx.x];
        __syncthreads();
        double b1 = 1e300; int k1 = 0x7fffffff;
        for (int k = threadIdx.x; k < K_CL; k += 256) {
            const float* c = C + (size_t)k * DIM;
            double acc = 0.0;
            for (int d = 0; d < DIM; ++d) acc += Frow[d] * (double)c[d];
            double dd = c2d[k] - 2.0 * acc;
            if (dd < b1 || (dd == b1 && k < k1)) { b1 = dd; k1 = k; }
        }
        bd[threadIdx.x] = b1; bk[threadIdx.x] = k1;
        __syncthreads();
        for (int s = 128; s > 0; s >>= 1) {
            if (threadIdx.x < s) {
                double ob = bd[threadIdx.x + s]; int ok = bk[threadIdx.x + s];
                if (ob < bd[threadIdx.x] || (ob == bd[threadIdx.x] && ok < bk[threadIdx.x])) {
                    bd[threadIdx.x] = ob; bk[threadIdx.x] = ok;
                }
            }
            __syncthreads();
        }
        if (threadIdx.x == 0) assign_out[p] = (float)bk[0];
        __syncthreads();
    }
}

// ---------------- kernel D v2: segment sum via K-range partition + queue ----------------
// grid = 4 K-ranges x SS_PARTS point partitions. Each block owns clusters
// [k0,k0+128) and points [s0,s1). Phase 1: scan assigns, enqueue owned points.
// Phase 2: coalesced full-row reads (128 lanes x 4B), LDS atomic accumulate,
// 4 loads in flight per thread. Phase 3: flush to global via unsafeAtomicAdd.
__global__ __launch_bounds__(256, 2)
void segsum2_kernel(const float* __restrict__ F, const float* __restrict__ assign_f,
                    float* __restrict__ sums, float* __restrict__ counts, int N) {
    __shared__ float acc[128 * 128];   // 64 KB  [localK][dim]
    __shared__ float cnt[128];
    __shared__ int   queue[QCAP];      // packed p*128 + localK
    __shared__ int   qn;

    const int tid    = threadIdx.x;
    const int krange = blockIdx.x & 3;
    const int part   = blockIdx.x >> 2;
    const int k0     = krange * 128;

    for (int i = tid; i < 128 * 128; i += 256) acc[i] = 0.f;
    if (tid < 128) cnt[tid] = 0.f;
    if (tid == 0) qn = 0;
    __syncthreads();

    const int per = (N + SS_PARTS - 1) / SS_PARTS;   // 1563
    int s0 = part * per;
    int s1 = s0 + per; if (s1 > N) s1 = N;

    // ---- phase 1: scan + enqueue ----
    for (int p = s0 + tid; p < s1; p += 256) {
        int a = (int)assign_f[p];
        int lc = a - k0;
        if ((unsigned)lc < 128u) {
            int idx = atomicAdd(&qn, 1);
            if (idx < QCAP) queue[idx] = p * 128 + lc;
            else {   // overflow fallback (statistically never)
                const float* row = F + (size_t)p * DIM;
                for (int d = 0; d < DIM; ++d)
                    unsafeAtomicAdd(&sums[(size_t)a * DIM + d], row[d]);
            }
            atomicAdd(&cnt[lc], 1.f);
        }
    }
    __syncthreads();

    // ---- phase 2: accumulate rows, 4 loads in flight ----
    int n = qn; if (n > QCAP) n = QCAP;
    int d   = tid & 127;
    int sub = tid >> 7;     // 0..1
    for (int q0 = sub; q0 < n; q0 += 8) {
        float v[4]; int lc[4];
#pragma unroll
        for (int t = 0; t < 4; ++t) {
            int q = q0 + 2 * t;
            if (q < n) {
                int pk = queue[q];
                lc[t] = pk & 127;
                v[t]  = F[(size_t)(pk >> 7) * DIM + d];
            } else lc[t] = -1;
        }
#pragma unroll
        for (int t = 0; t < 4; ++t)
            if (lc[t] >= 0) atomicAdd(&acc[lc[t] * 128 + d], v[t]);
    }
    __syncthreads();

    // ---- phase 3: flush ----
    for (int i = tid; i < 128 * 128; i += 256) {
        float v = acc[i];
        if (v != 0.f)
            unsafeAtomicAdd(&sums[(size_t)(k0 + (i >> 7)) * DIM + (i & 127)], v);
    }
    if (tid < 128) {
        float v = cnt[tid];
        if (v != 0.f) unsafeAtomicAdd(&counts[k0 + tid], v);
    }
}

// ---------------- kernel E: new_centers = sums / max(counts,1) ----------------
__global__ void finalize_kernel(const float* __restrict__ sums,
                                const float* __restrict__ counts,
                                float* __restrict__ out) {
    int i = blockIdx.x * 256 + threadIdx.x;   // 0..65535
    int k = i >> 7;
    out[i] = sums[i] / fmaxf(counts[k], 1.0f);
}

extern "C" void kernel_launch(void* const* d_in, const int* in_sizes, int n_in,
                              void* d_out, int out_size, void* d_ws, size_t ws_size,
                              hipStream_t stream) {
    const float* F = (const float*)d_in[0];
    const float* C = (const float*)d_in[1];
    int N = in_sizes[0] / DIM;               // 200000

    float* out = (float*)d_out;
    float* centers_out = out;                // [512*128]
    float* assign_out  = out + K_CL * DIM;   // [N], as float

    float*  sums      = (float*)d_ws;                     // 65536 f
    float*  counts    = sums + K_CL * DIM;                // 512 f
    int*    rescueCnt = (int*)(counts + K_CL);            // 4 i
    int*    rescueLst = rescueCnt + 4;                    // 16384 i
    float*  c2        = (float*)(rescueLst + RESCUE_CAP); // 512 f
    double* c2d       = (double*)(c2 + K_CL);             // 512 d
    ushort* Cp        = (ushort*)(c2d + K_CL);            // 512*256 us

    hipMemsetAsync(d_ws, 0, (size_t)(K_CL * DIM + K_CL) * sizeof(float) + 16, stream);

    c2_kernel<<<2, 256, 0, stream>>>(C, c2, c2d);
    convC_kernel<<<K_CL * DIM / 256, 256, 0, stream>>>(C, Cp);

    int nb = (N + BM - 1) / BM;              // 1563
    assign_mfma<<<nb, 256, 0, stream>>>(F, Cp, c2, assign_out, rescueCnt, rescueLst, N);

    rescue_kernel<<<256, 256, 0, stream>>>(F, C, c2d, rescueCnt, rescueLst, assign_out);

    segsum2_kernel<<<4 * SS_PARTS, 256, 0, stream>>>(F, assign_out, sums, counts, N);

    finalize_kernel<<<K_CL * DIM / 256, 256, 0, stream>>>(sums, counts, centers_out);
}

// Round 4
// 541.380 us; speedup vs baseline: 1.9145x; 1.0174x over previous
//
#include <hip/hip_runtime.h>

#define DIM 128
#define K_CL 512
#define BM 128          // points per block tile
#define CC 128          // centers per chunk (4 chunks)
#define TAU 0.02f       // margin below which we recompute in fp64
#define RESCUE_CAP 16384
#define SS_PARTS 128    // point partitions for segment-sum
#define QCAP 2048

typedef unsigned int uint;
typedef unsigned short ushort;
using short8 = __attribute__((ext_vector_type(8))) short;
using f32x4  = __attribute__((ext_vector_type(4))) float;
using us8    = __attribute__((ext_vector_type(8))) unsigned short;

__device__ __forceinline__ ushort f2bf(float x) {
    uint u = __float_as_uint(x);
    u += 0x7fff + ((u >> 16) & 1);          // RNE
    return (ushort)(u >> 16);
}
__device__ __forceinline__ float bf2f(ushort h) {
    return __uint_as_float(((uint)h) << 16);
}

__device__ __forceinline__ void gload_lds16(const void* gsrc, void* ldst) {
    __builtin_amdgcn_global_load_lds(
        (const __attribute__((address_space(1))) unsigned int*)gsrc,
        (__attribute__((address_space(3))) unsigned int*)ldst,
        16, 0, 0);
}

// ---------------- kernel A: c2 (fp32) and c2d (fp64) ----------------
__global__ void c2_kernel(const float* __restrict__ C, float* __restrict__ c2,
                          double* __restrict__ c2d) {
    int k = blockIdx.x * 256 + threadIdx.x;
    if (k < K_CL) {
        const float* row = C + (size_t)k * DIM;
        float s = 0.f;
        double sd = 0.0;
        for (int d = 0; d < DIM; ++d) {
            s = fmaf(row[d], row[d], s);
            double v = (double)row[d];
            sd += v * v;
        }
        c2[k] = s;
        c2d[k] = sd;
    }
}

// ---------------- kernel A2: split C into bf16 hi|lo ----------------
__global__ void convC_kernel(const float* __restrict__ C, ushort* __restrict__ Cp) {
    int e = blockIdx.x * 256 + threadIdx.x;   // 0..65535
    if (e < K_CL * DIM) {
        int p = e >> 7, d = e & 127;
        float x = C[e];
        ushort h = f2bf(x);
        float lo = x - bf2f(h);
        Cp[(size_t)p * 256 + d] = h;
        Cp[(size_t)p * 256 + 128 + d] = f2bf(lo);
    }
}

// ---------------- kernel B v2: MFMA distance GEMM + argmin ----------------
// 4-stage schedule per 128-center chunk:
//   st0: stage hiC[k0:64)   -> mfma vs hiF(ak0) AND loF(ak2)   (64 mfma)
//   st1: stage hiC[64:128)  -> mfma vs hiF(ak1) AND loF(ak3)   (64 mfma)
//   st2: stage loC[k0:64)   -> mfma vs hiF(ak0)                (32 mfma)
//   st3: stage loC[64:128)  -> mfma vs hiF(ak1)                (32 mfma)
// All LDS addresses precomputed in registers; inner loops fully unrolled so
// ds_read gets immediate offsets (kills the 40% VALUBusy of R3).
__global__ __launch_bounds__(256, 2)
void assign_mfma(const float* __restrict__ F, const ushort* __restrict__ Cp,
                 const float* __restrict__ c2g, float* __restrict__ assign_out,
                 int* __restrict__ rescueCnt, int* __restrict__ rescueLst, int N) {
    __shared__ __align__(16) ushort Fs[BM * 256];   // 65536 B
    __shared__ __align__(16) ushort Cs[CC * 64];    // 16384 B

    const int tid  = threadIdx.x;
    const int lane = tid & 63;
    const int wave = tid >> 6;
    const int quad = lane >> 4;
    const int l15  = lane & 15;
    const int wy   = wave >> 1;     // point half (0,1)
    const int wx   = wave & 1;      // center half (0,1)
    const int p0   = blockIdx.x * BM;

    // ---- stage Fs: read fp32 F, split to bf16 hi/lo, swizzled store ----
    for (int G = tid; G < BM * 32; G += 256) {
        int r = G >> 5, pos = G & 31;
        int g = (pos & 24) | ((pos ^ r) & 7);
        int gp = p0 + r; if (gp >= N) gp = N - 1;
        const float* src = F + (size_t)gp * DIM + (g & 15) * 8;
        float4 x0 = ((const float4*)src)[0];
        float4 x1 = ((const float4*)src)[1];
        float xs[8] = {x0.x, x0.y, x0.z, x0.w, x1.x, x1.y, x1.z, x1.w};
        us8 o;
        if (g < 16) {
#pragma unroll
            for (int t = 0; t < 8; ++t) o[t] = f2bf(xs[t]);
        } else {
#pragma unroll
            for (int t = 0; t < 8; ++t) {
                ushort h = f2bf(xs[t]);
                o[t] = f2bf(xs[t] - bf2f(h));
            }
        }
        *((us8*)&Fs[(size_t)G * 8]) = o;
    }

    // ---- precompute LDS read offsets (ushort elements) ----
    // A: elem = pr*256 + ak*64 + ((s*4+quad)^(pr&7))*8   (ak via imm)
    // B: elem = cn*64  +        ((s*4+quad)^(cn&7))*8
    int aoff[4][2], boff[4][2];
#pragma unroll
    for (int i = 0; i < 4; ++i) {
        int pr = wy * 64 + i * 16 + l15;
#pragma unroll
        for (int s = 0; s < 2; ++s)
            aoff[i][s] = pr * 256 + (((s * 4 + quad) ^ (pr & 7)) * 8);
    }
#pragma unroll
    for (int j = 0; j < 4; ++j) {
        int cn = wx * 64 + j * 16 + l15;
#pragma unroll
        for (int s = 0; s < 2; ++s)
            boff[j][s] = cn * 64 + (((s * 4 + quad) ^ (cn & 7)) * 8);
    }

    // ---- precompute staging source/dest offsets ----
    int cpoff[4];
    ushort* ldsdst[4];
#pragma unroll
    for (int t = 0; t < 4; ++t) {
        int Gbase = t * 256 + wave * 64;     // wave-uniform base granule
        int G = Gbase + lane;
        int r = G >> 3, pos = G & 7;
        int g = pos ^ (r & 7);
        cpoff[t] = r * 256 + g * 8;
        ldsdst[t] = &Cs[(size_t)Gbase * 8];
    }

    float best1[16], best2[16];
    int bidx[16];
#pragma unroll
    for (int i = 0; i < 16; ++i) { best1[i] = 3.4e38f; best2[i] = 3.4e38f; bidx[i] = 0; }

    for (int cc = 0; cc < K_CL / CC; ++cc) {
        const int ccbase = cc * (CC * 256);
        f32x4 acc[4][4];
#pragma unroll
        for (int i = 0; i < 4; ++i)
#pragma unroll
            for (int j = 0; j < 4; ++j) acc[i][j] = f32x4{0.f, 0.f, 0.f, 0.f};

#pragma unroll
        for (int st = 0; st < 4; ++st) {
            const int ak0 = st & 1;               // st0->0, st1->1, st2->0, st3->1
            const int ak1 = (st < 2) ? (st + 2) : -1;   // loF pair only for st0/1

            __syncthreads();   // Cs consumed by previous stage
#pragma unroll
            for (int t = 0; t < 4; ++t)
                gload_lds16(Cp + ccbase + st * 64 + cpoff[t], ldsdst[t]);
            __syncthreads();   // staging complete

#pragma unroll
            for (int s = 0; s < 2; ++s) {
                short8 b[4], a[4];
#pragma unroll
                for (int j = 0; j < 4; ++j)
                    b[j] = *((const short8*)&Cs[boff[j][s]]);
#pragma unroll
                for (int i = 0; i < 4; ++i)
                    a[i] = *((const short8*)&Fs[aoff[i][s] + ak0 * 64]);
#pragma unroll
                for (int i = 0; i < 4; ++i)
#pragma unroll
                    for (int j = 0; j < 4; ++j)
                        acc[i][j] = __builtin_amdgcn_mfma_f32_16x16x32_bf16(
                            a[i], b[j], acc[i][j], 0, 0, 0);
                if (ak1 >= 0) {
#pragma unroll
                    for (int i = 0; i < 4; ++i)
                        a[i] = *((const short8*)&Fs[aoff[i][s] + ak1 * 64]);
#pragma unroll
                    for (int i = 0; i < 4; ++i)
#pragma unroll
                        for (int j = 0; j < 4; ++j)
                            acc[i][j] = __builtin_amdgcn_mfma_f32_16x16x32_bf16(
                                a[i], b[j], acc[i][j], 0, 0, 0);
                }
            }
        }

        // ---- epilogue for this center chunk ----
        float c2v[4];
#pragma unroll
        for (int j = 0; j < 4; ++j)
            c2v[j] = c2g[cc * CC + wx * 64 + j * 16 + l15];
#pragma unroll
        for (int i = 0; i < 4; ++i)
#pragma unroll
            for (int reg = 0; reg < 4; ++reg) {
                int lr = i * 4 + reg;
#pragma unroll
                for (int j = 0; j < 4; ++j) {
                    float d = c2v[j] - 2.0f * acc[i][j][reg];
                    int k = cc * CC + wx * 64 + j * 16 + l15;
                    if (d < best1[lr]) { best2[lr] = best1[lr]; best1[lr] = d; bidx[lr] = k; }
                    else if (d < best2[lr]) best2[lr] = d;
                }
            }
    }

    // ---- reduce across the 16 l15 lanes ----
    __syncthreads();
    float* sb1 = (float*)Cs;                 // [2][128]
    float* sb2 = sb1 + 256;
    int*   sk  = (int*)(sb2 + 256);

#pragma unroll
    for (int lr = 0; lr < 16; ++lr) {
        float b1 = best1[lr], b2 = best2[lr];
        int k1 = bidx[lr];
#pragma unroll
        for (int m = 1; m <= 8; m <<= 1) {
            float ob1 = __shfl_xor(b1, m);
            float ob2 = __shfl_xor(b2, m);
            int   ok1 = __shfl_xor(k1, m);
            float nb2 = fminf(fmaxf(b1, ob1), fminf(b2, ob2));
            if (ob1 < b1 || (ob1 == b1 && ok1 < k1)) { b1 = ob1; k1 = ok1; }
            b2 = nb2;
        }
        best1[lr] = b1; best2[lr] = b2; bidx[lr] = k1;
    }
    if (l15 == 0) {
#pragma unroll
        for (int lr = 0; lr < 16; ++lr) {
            int pl = wy * 64 + (lr >> 2) * 16 + quad * 4 + (lr & 3);
            sb1[wx * 128 + pl] = best1[lr];
            sb2[wx * 128 + pl] = best2[lr];
            sk [wx * 128 + pl] = bidx[lr];
        }
    }
    __syncthreads();

    if (tid < BM) {
        int p = p0 + tid;
        if (p < N) {
            float a1 = sb1[tid],       a2 = sb2[tid];        int akk = sk[tid];
            float c1 = sb1[128 + tid], cs2 = sb2[128 + tid]; int ckk = sk[128 + tid];
            float m2 = fminf(fmaxf(a1, c1), fminf(a2, cs2));
            float m1; int mk;
            if (c1 < a1 || (c1 == a1 && ckk < akk)) { m1 = c1; mk = ckk; }
            else                                    { m1 = a1; mk = akk; }
            assign_out[p] = (float)mk;
            if (m2 - m1 < TAU) {
                int idx = atomicAdd(rescueCnt, 1);
                if (idx < RESCUE_CAP) rescueLst[idx] = p;
            }
        }
    }
}

// ---------------- kernel C: fp64 re-argmin for near-tie points ----------------
__global__ void rescue_kernel(const float* __restrict__ F, const float* __restrict__ C,
                              const double* __restrict__ c2d,
                              const int* __restrict__ rescueCnt,
                              const int* __restrict__ rescueLst,
                              float* __restrict__ assign_out) {
    __shared__ double Frow[DIM];
    __shared__ double bd[256];
    __shared__ int    bk[256];
    int cnt = *rescueCnt;
    if (cnt > RESCUE_CAP) cnt = RESCUE_CAP;
    for (int r = blockIdx.x; r < cnt; r += gridDim.x) {
        int p = rescueLst[r];
        if (threadIdx.x < DIM) Frow[threadIdx.x] = (double)F[(size_t)p * DIM + threadIdx.x];
        __syncthreads();
        double b1 = 1e300; int k1 = 0x7fffffff;
        for (int k = threadIdx.x; k < K_CL; k += 256) {
            const float* c = C + (size_t)k * DIM;
            double acc = 0.0;
            for (int d = 0; d < DIM; ++d) acc += Frow[d] * (double)c[d];
            double dd = c2d[k] - 2.0 * acc;
            if (dd < b1 || (dd == b1 && k < k1)) { b1 = dd; k1 = k; }
        }
        bd[threadIdx.x] = b1; bk[threadIdx.x] = k1;
        __syncthreads();
        for (int s = 128; s > 0; s >>= 1) {
            if (threadIdx.x < s) {
                double ob = bd[threadIdx.x + s]; int ok = bk[threadIdx.x + s];
                if (ob < bd[threadIdx.x] || (ob == bd[threadIdx.x] && ok < bk[threadIdx.x])) {
                    bd[threadIdx.x] = ob; bk[threadIdx.x] = ok;
                }
            }
            __syncthreads();
        }
        if (threadIdx.x == 0) assign_out[p] = (float)bk[0];
        __syncthreads();
    }
}

// ---------------- kernel D v2: segment sum via K-range partition + queue ----------------
__global__ __launch_bounds__(256, 2)
void segsum2_kernel(const float* __restrict__ F, const float* __restrict__ assign_f,
                    float* __restrict__ sums, float* __restrict__ counts, int N) {
    __shared__ float acc[128 * 128];   // 64 KB  [localK][dim]
    __shared__ float cnt[128];
    __shared__ int   queue[QCAP];      // packed p*128 + localK
    __shared__ int   qn;

    const int tid    = threadIdx.x;
    const int krange = blockIdx.x & 3;
    const int part   = blockIdx.x >> 2;
    const int k0     = krange * 128;

    for (int i = tid; i < 128 * 128; i += 256) acc[i] = 0.f;
    if (tid < 128) cnt[tid] = 0.f;
    if (tid == 0) qn = 0;
    __syncthreads();

    const int per = (N + SS_PARTS - 1) / SS_PARTS;   // 1563
    int s0 = part * per;
    int s1 = s0 + per; if (s1 > N) s1 = N;

    for (int p = s0 + tid; p < s1; p += 256) {
        int a = (int)assign_f[p];
        int lc = a - k0;
        if ((unsigned)lc < 128u) {
            int idx = atomicAdd(&qn, 1);
            if (idx < QCAP) queue[idx] = p * 128 + lc;
            else {
                const float* row = F + (size_t)p * DIM;
                for (int d = 0; d < DIM; ++d)
                    unsafeAtomicAdd(&sums[(size_t)a * DIM + d], row[d]);
            }
            atomicAdd(&cnt[lc], 1.f);
        }
    }
    __syncthreads();

    int n = qn; if (n > QCAP) n = QCAP;
    int d   = tid & 127;
    int sub = tid >> 7;     // 0..1
    for (int q0 = sub; q0 < n; q0 += 8) {
        float v[4]; int lc[4];
#pragma unroll
        for (int t = 0; t < 4; ++t) {
            int q = q0 + 2 * t;
            if (q < n) {
                int pk = queue[q];
                lc[t] = pk & 127;
                v[t]  = F[(size_t)(pk >> 7) * DIM + d];
            } else lc[t] = -1;
        }
#pragma unroll
        for (int t = 0; t < 4; ++t)
            if (lc[t] >= 0) atomicAdd(&acc[lc[t] * 128 + d], v[t]);
    }
    __syncthreads();

    for (int i = tid; i < 128 * 128; i += 256) {
        float v = acc[i];
        if (v != 0.f)
            unsafeAtomicAdd(&sums[(size_t)(k0 + (i >> 7)) * DIM + (i & 127)], v);
    }
    if (tid < 128) {
        float v = cnt[tid];
        if (v != 0.f) unsafeAtomicAdd(&counts[k0 + tid], v);
    }
}

// ---------------- kernel E: new_centers = sums / max(counts,1) ----------------
__global__ void finalize_kernel(const float* __restrict__ sums,
                                const float* __restrict__ counts,
                                float* __restrict__ out) {
    int i = blockIdx.x * 256 + threadIdx.x;   // 0..65535
    int k = i >> 7;
    out[i] = sums[i] / fmaxf(counts[k], 1.0f);
}

extern "C" void kernel_launch(void* const* d_in, const int* in_sizes, int n_in,
                              void* d_out, int out_size, void* d_ws, size_t ws_size,
                              hipStream_t stream) {
    const float* F = (const float*)d_in[0];
    const float* C = (const float*)d_in[1];
    int N = in_sizes[0] / DIM;               // 200000

    float* out = (float*)d_out;
    float* centers_out = out;                // [512*128]
    float* assign_out  = out + K_CL * DIM;   // [N], as float

    float*  sums      = (float*)d_ws;                     // 65536 f
    float*  counts    = sums + K_CL * DIM;                // 512 f
    int*    rescueCnt = (int*)(counts + K_CL);            // 4 i
    int*    rescueLst = rescueCnt + 4;                    // 16384 i
    float*  c2        = (float*)(rescueLst + RESCUE_CAP); // 512 f
    double* c2d       = (double*)(c2 + K_CL);             // 512 d
    ushort* Cp        = (ushort*)(c2d + K_CL);            // 512*256 us

    hipMemsetAsync(d_ws, 0, (size_t)(K_CL * DIM + K_CL) * sizeof(float) + 16, stream);

    c2_kernel<<<2, 256, 0, stream>>>(C, c2, c2d);
    convC_kernel<<<K_CL * DIM / 256, 256, 0, stream>>>(C, Cp);

    int nb = (N + BM - 1) / BM;              // 1563
    assign_mfma<<<nb, 256, 0, stream>>>(F, Cp, c2, assign_out, rescueCnt, rescueLst, N);

    rescue_kernel<<<256, 256, 0, stream>>>(F, C, c2d, rescueCnt, rescueLst, assign_out);

    segsum2_kernel<<<4 * SS_PARTS, 256, 0, stream>>>(F, assign_out, sums, counts, N);

    finalize_kernel<<<K_CL * DIM / 256, 256, 0, stream>>>(sums, counts, centers_out);
}